// Round 5
// baseline (318.831 us; speedup 1.0000x reference)
//
#include <hip/hip_runtime.h>
#include <hip/hip_cooperative_groups.h>
#include <stdint.h>

namespace cg = cooperative_groups;

// Problem constants (from reference)
#define B_   8
#define N_   1024
#define C_   256      // C == C_OUT == 256
#define E_   16384
#define BN_  (B_ * N_)        // 8192
#define NW_  (N_ / 32)        // 32 mask words per row
#define LIST_CAP 96           // per-wave LDS neighbor list; Poisson(16) tail ~0
#define GRID_ 512             // cooperative grid: 2 blocks/CU on 256 CUs

typedef __attribute__((ext_vector_type(8))) short bf16x8;
typedef __attribute__((ext_vector_type(4))) float f32x4;

static __device__ __forceinline__ short f32_to_bf16(float f) {
  uint32_t u = __float_as_uint(f);
  uint32_t r = (u + 0x7fffu + ((u >> 16) & 1u)) >> 16;   // RNE
  return (short)r;
}
static __device__ __forceinline__ float bf16_to_f32(short s) {
  return __uint_as_float(((uint32_t)(uint16_t)s) << 16);
}

// ---------------------------------------------------------------------------
// Single cooperative kernel, 512 blocks x 256 threads (2 blocks/CU resident):
//  A) zero the 1 MB mask (replaces hipMemsetAsync dispatch)
//     -- threadfence (L2 writeback so device-scope atomics see zeros) + grid.sync
//  B) scatter: 1 edge/thread (device-scope atomicOr, coherent at IF$)
//     gemm:    Y = X @ W^T, bf16x3 split MFMA (fp32-grade accuracy),
//              64x64 tile, BK=32; block b: m-tile b>>2, n-tile b&3
//     -- threadfence (wbl2: Y + mask dirty lines) + grid.sync + threadfence (inv)
//  C) aggregate: out[i] = dinv_i*(dinv_i*Y[i] + sum_j dinv_j*Y[j]) + bias,
//     one wave per node, 4 node-groups per block.
__global__ __launch_bounds__(256, 2) void gcn_fused(
    const float* __restrict__ X, const float* __restrict__ W,
    const int* __restrict__ ei, const float* __restrict__ bias,
    uint32_t* __restrict__ mask, float* __restrict__ Y,
    float* __restrict__ out) {
  // pad 32 -> 40 shorts/row: b128 frag reads land 8 words/bank (optimal)
  __shared__ __attribute__((aligned(16))) short Ah[64][40];
  __shared__ __attribute__((aligned(16))) short Al[64][40];
  __shared__ __attribute__((aligned(16))) short Bh[64][40];
  __shared__ __attribute__((aligned(16))) short Bl[64][40];
  __shared__ uint16_t lists[4][LIST_CAP];
  __shared__ float    wgts[4][LIST_CAP];

  cg::grid_group grid = cg::this_grid();
  int t   = threadIdx.x;
  int tid = blockIdx.x * 256 + t;                  // 0 .. 131071

  // ======== phase A: zero mask (262144 words = 2 per thread) ========
  ((uint2*)mask)[tid] = make_uint2(0u, 0u);
  __threadfence();               // wbl2: zeros visible at coherence point
  grid.sync();

  // ======== phase B: edge scatter (1 edge/thread) + GEMM ========
  {
    int b   = tid & (B_ - 1);                      // edge layout [E, B]
    int src = ei[tid];                             // edge_index[0] flat
    int dst = ei[E_ * B_ + tid];                   // edge_index[1] flat
    atomicOr(&mask[(size_t)(b * N_ + src) * NW_ + (dst >> 5)],
             1u << (dst & 31));
  }

  int m0 = (blockIdx.x >> 2) * 64;
  int n0 = (blockIdx.x & 3) * 64;
  int lr = t >> 2;               // staging row 0..63
  int lc = (t & 3) * 8;          // staging col base (8 floats)
  int wv = t >> 6;               // wave 0..3
  int ln = t & 63;
  int lm = ln & 15;              // frag row-in-tile
  int qd = ln >> 4;              // frag k-quad

  f32x4 acc[4];
#pragma unroll
  for (int i = 0; i < 4; i++) acc[i] = (f32x4){0.f, 0.f, 0.f, 0.f};

  for (int k0 = 0; k0 < C_; k0 += 32) {
    // ---- stage: fp32 -> (hi, lo) bf16 split ----
    const float* xr = &X[(size_t)(m0 + lr) * C_ + k0 + lc];
    const float* wr = &W[(size_t)(n0 + lr) * C_ + k0 + lc];
    float xv[8], wv8[8];
    *(float4*)&xv[0] = *(const float4*)&xr[0];
    *(float4*)&xv[4] = *(const float4*)&xr[4];
    *(float4*)&wv8[0] = *(const float4*)&wr[0];
    *(float4*)&wv8[4] = *(const float4*)&wr[4];
    bf16x8 xh, xl, wh, wl;
#pragma unroll
    for (int j = 0; j < 8; j++) {
      short h = f32_to_bf16(xv[j]);
      xh[j] = h;
      xl[j] = f32_to_bf16(xv[j] - bf16_to_f32(h));
      short g = f32_to_bf16(wv8[j]);
      wh[j] = g;
      wl[j] = f32_to_bf16(wv8[j] - bf16_to_f32(g));
    }
    __syncthreads();               // prev iter's frag reads done
    *(bf16x8*)&Ah[lr][lc] = xh;
    *(bf16x8*)&Al[lr][lc] = xl;
    *(bf16x8*)&Bh[lr][lc] = wh;
    *(bf16x8*)&Bl[lr][lc] = wl;
    __syncthreads();

    // ---- MFMA: D += Ah*Bh + Ah*Bl + Al*Bh ----
    bf16x8 ah = *(const bf16x8*)&Ah[16 * wv + lm][qd * 8];
    bf16x8 al = *(const bf16x8*)&Al[16 * wv + lm][qd * 8];
#pragma unroll
    for (int nt = 0; nt < 4; nt++) {
      bf16x8 bh = *(const bf16x8*)&Bh[nt * 16 + lm][qd * 8];
      bf16x8 bl = *(const bf16x8*)&Bl[nt * 16 + lm][qd * 8];
      acc[nt] = __builtin_amdgcn_mfma_f32_16x16x32_bf16(ah, bh, acc[nt], 0, 0, 0);
      acc[nt] = __builtin_amdgcn_mfma_f32_16x16x32_bf16(ah, bl, acc[nt], 0, 0, 0);
      acc[nt] = __builtin_amdgcn_mfma_f32_16x16x32_bf16(al, bh, acc[nt], 0, 0, 0);
    }
  }

  // epilogue: raw Y. C/D layout: n(col) = lane&15, m(row) = (lane>>4)*4 + reg
#pragma unroll
  for (int nt = 0; nt < 4; nt++) {
#pragma unroll
    for (int r = 0; r < 4; r++) {
      int m = m0 + 16 * wv + qd * 4 + r;
      int n = n0 + nt * 16 + lm;
      Y[(size_t)m * C_ + n] = acc[nt][r];
    }
  }

  __threadfence();               // release: wbl2 (Y, mask) to coherence point
  grid.sync();
  __threadfence();               // acquire: inv stale local-L2 lines

  // ======== phase C: aggregate, 4 node-groups per block ========
  for (int it = 0; it < 4; it++) {
    int vblk  = it * GRID_ + blockIdx.x;           // 0..2047
    int batch = vblk & 7;                          // == blockIdx.x & 7 (XCD)
    int group = vblk >> 3;                         // 0..255
    int loc   = group * 4 + wv;                    // local node 0..1023
    int node  = batch * N_ + loc;
    int c4    = ln * 4;

    const uint32_t* mb = mask + (size_t)batch * N_ * NW_;

    // ---- build neighbor list in LDS (wave-synchronous) ----
    uint32_t bits = (ln < NW_) ? mb[(size_t)loc * NW_ + ln] : 0u;
    int cnt = __popc(bits);
    int pfx = cnt;
#pragma unroll
    for (int off = 1; off < 64; off <<= 1) {
      int v = __shfl_up(pfx, off);
      if (ln >= off) pfx += v;
    }
    int total = __shfl(pfx, 63);     // own degree (excluding self loop)
    pfx -= cnt;                      // exclusive prefix
    uint16_t* lst = lists[wv];
    float*    wgt = wgts[wv];
    int o = pfx, jb = ln * 32;
    while (bits) {
      int j = __ffs(bits) - 1;
      bits &= bits - 1;
      lst[o++] = (uint16_t)(jb + j);
    }
    if (ln == 0) {                   // pad to multiple of 4, weight 0
      int dd = total;
      while (dd & 3) { lst[dd] = 0; wgt[dd] = 0.f; dd++; }
    }
    // same-wave LDS write->read: lockstep wave64, program-order ds ops.

    // ---- neighbor dinv_j: 2 neighbors per iter (32-lane halves) ----
    int half = ln >> 5;              // 0 or 1
    int wl   = ln & 31;
    for (int k = 0; k < total; k += 2) {
      int kk = k + half;
      int nj = (kk < total) ? lst[kk] : 0;
      int p  = __popc(mb[(size_t)nj * NW_ + wl]);
      p += __shfl_xor(p, 1);  p += __shfl_xor(p, 2);  p += __shfl_xor(p, 4);
      p += __shfl_xor(p, 8);  p += __shfl_xor(p, 16); // stays in 32-lane half
      if (wl == 0 && kk < total) wgt[kk] = rsqrtf((float)(p + 1));
    }

    const float* yb = Y + (size_t)batch * N_ * C_;
    float di = rsqrtf((float)(total + 1));
    float4 s = *(const float4*)&yb[(size_t)loc * C_ + c4];
    float4 a4;                       // self (eye) term: dinv_i * Y[i]
    a4.x = di * s.x; a4.y = di * s.y; a4.z = di * s.z; a4.w = di * s.w;

    for (int k = 0; k < total; k += 4) {
      ushort4 n4 = *(const ushort4*)&lst[k];
      float4  w4 = *(const float4*)&wgt[k];
      float4 z0 = *(const float4*)&yb[(size_t)n4.x * C_ + c4];
      float4 z1 = *(const float4*)&yb[(size_t)n4.y * C_ + c4];
      float4 z2 = *(const float4*)&yb[(size_t)n4.z * C_ + c4];
      float4 z3 = *(const float4*)&yb[(size_t)n4.w * C_ + c4];
      a4.x += w4.x * z0.x; a4.y += w4.x * z0.y; a4.z += w4.x * z0.z; a4.w += w4.x * z0.w;
      a4.x += w4.y * z1.x; a4.y += w4.y * z1.y; a4.z += w4.y * z1.z; a4.w += w4.y * z1.w;
      a4.x += w4.z * z2.x; a4.y += w4.z * z2.y; a4.z += w4.z * z2.z; a4.w += w4.z * z2.w;
      a4.x += w4.w * z3.x; a4.y += w4.w * z3.y; a4.z += w4.w * z3.z; a4.w += w4.w * z3.w;
    }

    float4 bb = *(const float4*)&bias[c4];
    float4 o4;
    o4.x = di * a4.x + bb.x;
    o4.y = di * a4.y + bb.y;
    o4.z = di * a4.z + bb.z;
    o4.w = di * a4.w + bb.w;
    *(float4*)&out[(size_t)node * C_ + c4] = o4;
  }
}

// ---------------------------------------------------------------------------
extern "C" void kernel_launch(void* const* d_in, const int* in_sizes, int n_in,
                              void* d_out, int out_size, void* d_ws,
                              size_t ws_size, hipStream_t stream) {
  const float* x    = (const float*)d_in[0];   // [B,N,C]
  const int*   ei   = (const int*)d_in[1];     // [2,E,B]
  const float* W    = (const float*)d_in[2];   // [C_OUT,C]
  const float* bias = (const float*)d_in[3];   // [C_OUT]
  float*       out  = (float*)d_out;           // [B,N,C_OUT]

  // workspace layout (byte offsets):
  //   mask @ 0x000000  1 MB   (BN_*NW_*4)
  //   Y    @ 0x100000  8 MB
  char* ws = (char*)d_ws;
  uint32_t* mask = (uint32_t*)(ws + 0x000000);
  float*    Y    = (float*)   (ws + 0x100000);

  void* args[] = {(void*)&x, (void*)&W, (void*)&ei, (void*)&bias,
                  (void*)&mask, (void*)&Y, (void*)&out};
  hipLaunchCooperativeKernel((void*)gcn_fused, dim3(GRID_), dim3(256),
                             args, 0, stream);
}

// Round 6
// 96.214 us; speedup vs baseline: 3.3138x; 3.3138x over previous
//
#include <hip/hip_runtime.h>
#include <stdint.h>

// Problem constants (from reference)
#define B_   8
#define N_   1024
#define C_   256      // C == C_OUT == 256
#define E_   16384
#define BN_  (B_ * N_)        // 8192
#define NW_  (N_ / 32)        // 32 mask words per row
#define LIST_CAP 96           // per-wave LDS neighbor list; Poisson(16) tail ~0

typedef __attribute__((ext_vector_type(8))) short bf16x8;
typedef __attribute__((ext_vector_type(4))) float f32x4;

static __device__ __forceinline__ short f32_to_bf16(float f) {
  uint32_t u = __float_as_uint(f);
  uint32_t r = (u + 0x7fffu + ((u >> 16) & 1u)) >> 16;   // RNE
  return (short)r;
}
static __device__ __forceinline__ float bf16_to_f32(short s) {
  return __uint_as_float(((uint32_t)(uint16_t)s) << 16);
}

// ---------------------------------------------------------------------------
// 1) Scatter edges into per-(batch,src) dst-bitmask. atomicOr == .set(1.0)
//    dedup semantics (duplicate edges count once).
__global__ __launch_bounds__(256) void scatter_edges(
    const int* __restrict__ ei, uint32_t* __restrict__ mask) {
  int t = blockIdx.x * 256 + threadIdx.x;          // 0 .. E_*B_-1
  if (t >= E_ * B_) return;
  int b   = t & (B_ - 1);                          // layout [E, B]
  int src = ei[t];                                 // edge_index[0] flat
  int dst = ei[E_ * B_ + t];                       // edge_index[1] flat
  int row = b * N_ + src;
  atomicOr(&mask[row * NW_ + (dst >> 5)], 1u << (dst & 31));
}

// ---------------------------------------------------------------------------
// 2) Z = dinv[m] * (X @ W^T)[m]  via bf16x3 split MFMA (fp32-grade accuracy).
//    dinv computed INLINE from the mask (popcount+1), no separate kernel.
//    Block tile 64(M) x 64(N), BK=32, 4 waves; wave w: rows [16w,16w+16) x 64.
__global__ __launch_bounds__(256) void gemm_bf16x3(
    const float* __restrict__ X, const float* __restrict__ W,
    const uint32_t* __restrict__ mask, float* __restrict__ Z) {
  // pad 32 -> 40 shorts/row: b128 frag reads land 8 words/bank (optimal)
  __shared__ __attribute__((aligned(16))) short Ah[64][40];
  __shared__ __attribute__((aligned(16))) short Al[64][40];
  __shared__ __attribute__((aligned(16))) short Bh[64][40];
  __shared__ __attribute__((aligned(16))) short Bl[64][40];
  __shared__ int   dpart[4][64];
  __shared__ float dinv_s[64];

  int t  = threadIdx.x;
  int m0 = blockIdx.x * 64;
  int n0 = blockIdx.y * 64;

  // ---- inline degree: popcount of mask rows m0..m0+63 ----
  {
    int row = t & 63, part = t >> 6;               // 4 threads per row
    const uint4* mp =
        (const uint4*)&mask[(size_t)(m0 + row) * NW_ + part * 8];
    uint4 a = mp[0], b = mp[1];
    dpart[part][row] = __popc(a.x) + __popc(a.y) + __popc(a.z) + __popc(a.w) +
                       __popc(b.x) + __popc(b.y) + __popc(b.z) + __popc(b.w);
  }
  __syncthreads();
  if (t < 64) {
    int d = dpart[0][t] + dpart[1][t] + dpart[2][t] + dpart[3][t] + 1;
    dinv_s[t] = rsqrtf((float)d);
  }
  // dinv_s is read only in the epilogue; the k-loop's syncthreads cover it.

  int lr = t >> 2;               // staging row 0..63
  int lc = (t & 3) * 8;          // staging col base (8 floats)
  int wv = t >> 6;               // wave 0..3
  int ln = t & 63;
  int lm = ln & 15;              // frag row-in-tile
  int qd = ln >> 4;              // frag k-quad

  f32x4 acc[4];
#pragma unroll
  for (int i = 0; i < 4; i++) acc[i] = (f32x4){0.f, 0.f, 0.f, 0.f};

  for (int k0 = 0; k0 < C_; k0 += 32) {
    // ---- stage: fp32 -> (hi, lo) bf16 split ----
    const float* xr = &X[(size_t)(m0 + lr) * C_ + k0 + lc];
    const float* wr = &W[(size_t)(n0 + lr) * C_ + k0 + lc];
    float xv[8], wv8[8];
    *(float4*)&xv[0] = *(const float4*)&xr[0];
    *(float4*)&xv[4] = *(const float4*)&xr[4];
    *(float4*)&wv8[0] = *(const float4*)&wr[0];
    *(float4*)&wv8[4] = *(const float4*)&wr[4];
    bf16x8 xh, xl, wh, wl;
#pragma unroll
    for (int j = 0; j < 8; j++) {
      short h = f32_to_bf16(xv[j]);
      xh[j] = h;
      xl[j] = f32_to_bf16(xv[j] - bf16_to_f32(h));
      short g = f32_to_bf16(wv8[j]);
      wh[j] = g;
      wl[j] = f32_to_bf16(wv8[j] - bf16_to_f32(g));
    }
    __syncthreads();               // also covers dinv_s write on first iter
    *(bf16x8*)&Ah[lr][lc] = xh;
    *(bf16x8*)&Al[lr][lc] = xl;
    *(bf16x8*)&Bh[lr][lc] = wh;
    *(bf16x8*)&Bl[lr][lc] = wl;
    __syncthreads();

    // ---- MFMA: D += Ah*Bh + Ah*Bl + Al*Bh ----
    bf16x8 ah = *(const bf16x8*)&Ah[16 * wv + lm][qd * 8];
    bf16x8 al = *(const bf16x8*)&Al[16 * wv + lm][qd * 8];
#pragma unroll
    for (int nt = 0; nt < 4; nt++) {
      bf16x8 bh = *(const bf16x8*)&Bh[nt * 16 + lm][qd * 8];
      bf16x8 bl = *(const bf16x8*)&Bl[nt * 16 + lm][qd * 8];
      acc[nt] = __builtin_amdgcn_mfma_f32_16x16x32_bf16(ah, bh, acc[nt], 0, 0, 0);
      acc[nt] = __builtin_amdgcn_mfma_f32_16x16x32_bf16(ah, bl, acc[nt], 0, 0, 0);
      acc[nt] = __builtin_amdgcn_mfma_f32_16x16x32_bf16(al, bh, acc[nt], 0, 0, 0);
    }
  }
  __syncthreads();   // ensure dinv_s visible (and LDS quiesced) before epilogue

  // ---- epilogue: Z[m][n] = dinv[m] * acc ----
  // C/D layout: n(col) = lane&15, m(row) = (lane>>4)*4 + reg
  float di[4];
#pragma unroll
  for (int r = 0; r < 4; r++) di[r] = dinv_s[16 * wv + qd * 4 + r];
#pragma unroll
  for (int nt = 0; nt < 4; nt++) {
#pragma unroll
    for (int r = 0; r < 4; r++) {
      int m = m0 + 16 * wv + qd * 4 + r;
      int n = n0 + nt * 16 + lm;
      Z[(size_t)m * C_ + n] = di[r] * acc[nt][r];
    }
  }
}

// ---------------------------------------------------------------------------
// 3) out[i] = dinv[i] * (Z[i] + sum_{j in mask(i)} Z[j]) + bias
//    One wave per node. Wave reads its 128B mask row (lane w owns word w),
//    shfl prefix-sum -> neighbor list in per-wave LDS, then unroll-4 float4
//    gathers. dinv[i] computed in-wave (popcount total + 1). XCD swizzle:
//    batch = blockIdx & 7 keeps each XCD's gather in its 1 MB batch slice.
__global__ __launch_bounds__(256) void aggregate(
    const uint32_t* __restrict__ mask, const float* __restrict__ Z,
    const float* __restrict__ bias, float* __restrict__ out) {
  __shared__ uint16_t lists[4][LIST_CAP];

  int blk   = blockIdx.x;            // 0..2047
  int batch = blk & 7;
  int group = blk >> 3;              // 0..255
  int wv    = threadIdx.x >> 6;      // wave 0..3 -> node within group
  int ln    = threadIdx.x & 63;
  int loc   = group * 4 + wv;        // local node 0..1023
  int node  = batch * N_ + loc;
  int c4    = ln * 4;

  // ---- build neighbor list in LDS (wave-synchronous) ----
  uint32_t bits = (ln < NW_) ? mask[(size_t)node * NW_ + ln] : 0u;
  int cnt = __popc(bits);
  int pfx = cnt;
#pragma unroll
  for (int off = 1; off < 64; off <<= 1) {
    int v = __shfl_up(pfx, off);
    if (ln >= off) pfx += v;
  }
  int total = __shfl(pfx, 63);       // degree (excluding self loop)
  pfx -= cnt;                        // exclusive prefix
  uint16_t* lst = lists[wv];
  int o = pfx, jb = ln * 32;
  while (bits) {
    int j = __ffs(bits) - 1;
    bits &= bits - 1;
    lst[o++] = (uint16_t)(jb + j);
  }
  if (ln == 0) {                     // pad to multiple of 4 (weight-0 below)
    int dd = total;
    while (dd & 3) lst[dd++] = 0;
  }
  // same-wave LDS write->read: lockstep wave64, program-order ds ops.

  const float* zb = Z + (size_t)batch * N_ * C_;
  float4 acc = *(const float4*)&zb[(size_t)loc * C_ + c4];   // self (eye) term

  for (int k = 0; k < total; k += 4) {
    ushort4 n4 = *(const ushort4*)&lst[k];
    float4 z0 = *(const float4*)&zb[(size_t)n4.x * C_ + c4];
    float4 z1 = *(const float4*)&zb[(size_t)n4.y * C_ + c4];
    float4 z2 = *(const float4*)&zb[(size_t)n4.z * C_ + c4];
    float4 z3 = *(const float4*)&zb[(size_t)n4.w * C_ + c4];
    float w1 = (k + 1 < total) ? 1.f : 0.f;
    float w2 = (k + 2 < total) ? 1.f : 0.f;
    float w3 = (k + 3 < total) ? 1.f : 0.f;
    acc.x += z0.x; acc.y += z0.y; acc.z += z0.z; acc.w += z0.w;
    acc.x += w1 * z1.x; acc.y += w1 * z1.y; acc.z += w1 * z1.z; acc.w += w1 * z1.w;
    acc.x += w2 * z2.x; acc.y += w2 * z2.y; acc.z += w2 * z2.z; acc.w += w2 * z2.w;
    acc.x += w3 * z3.x; acc.y += w3 * z3.y; acc.z += w3 * z3.z; acc.w += w3 * z3.w;
  }

  float di = rsqrtf((float)(total + 1));
  float4 bb = *(const float4*)&bias[c4];
  float4 o4;
  o4.x = di * acc.x + bb.x;
  o4.y = di * acc.y + bb.y;
  o4.z = di * acc.z + bb.z;
  o4.w = di * acc.w + bb.w;
  *(float4*)&out[(size_t)node * C_ + c4] = o4;
}

// ---------------------------------------------------------------------------
extern "C" void kernel_launch(void* const* d_in, const int* in_sizes, int n_in,
                              void* d_out, int out_size, void* d_ws,
                              size_t ws_size, hipStream_t stream) {
  const float* x    = (const float*)d_in[0];   // [B,N,C]
  const int*   ei   = (const int*)d_in[1];     // [2,E,B]
  const float* W    = (const float*)d_in[2];   // [C_OUT,C]
  const float* bias = (const float*)d_in[3];   // [C_OUT]
  float*       out  = (float*)d_out;           // [B,N,C_OUT]

  // workspace layout (byte offsets):
  //   mask @ 0x000000  1 MB   (BN_*NW_*4)
  //   Z    @ 0x100000  8 MB
  char* ws = (char*)d_ws;
  uint32_t* mask = (uint32_t*)(ws + 0x000000);
  float*    Z    = (float*)   (ws + 0x100000);

  hipMemsetAsync(mask, 0, (size_t)BN_ * NW_ * 4, stream);

  scatter_edges<<<(E_ * B_) / 256, 256, 0, stream>>>(ei, mask);
  gemm_bf16x3<<<dim3(BN_ / 64, C_ / 64), 256, 0, stream>>>(x, W, mask, Z);
  aggregate<<<BN_ / 4, 256, 0, stream>>>(mask, Z, bias, out);
}